// Round 1
// baseline (261.585 us; speedup 1.0000x reference)
//
#include <hip/hip_runtime.h>

#define BB 16
#define TT 2048
#define DD 768
#define HH 96

typedef __attribute__((ext_vector_type(8))) short bf16x8;
typedef __attribute__((ext_vector_type(4))) short bf16x4;
typedef __attribute__((ext_vector_type(4))) float f32x4;

static __device__ __forceinline__ unsigned short f2bf(float f) {
  unsigned u = __builtin_bit_cast(unsigned, f);
  u = (u + 0x7fffu + ((u >> 16) & 1u)) >> 16;   // round-to-nearest-even
  return (unsigned short)u;
}

// ---------------- W convert: Wt[w][n][k] bf16, w order = {q,k,v} ----------------
__global__ void wconv(const float* __restrict__ Wk, const float* __restrict__ Wq,
                      const float* __restrict__ Wv, unsigned short* __restrict__ Wt) {
  int idx = blockIdx.x * 256 + threadIdx.x;
  if (idx >= 3 * HH * DD) return;
  int w = idx / (HH * DD);
  int rem = idx - w * (HH * DD);
  int n = rem / DD;
  int k = rem - n * DD;
  const float* W = (w == 0) ? Wq : (w == 1) ? Wk : Wv;
  Wt[idx] = f2bf(W[k * HH + n]);
}

// ---------------- QKV projection ----------------
// grid 512, block 256 (4 waves). Wave: 16 rows x 96 cols, K=768.
__global__ __launch_bounds__(256) void qkv_proj(
    const float* __restrict__ x, const unsigned short* __restrict__ Wt,
    unsigned short* __restrict__ Qb, unsigned short* __restrict__ Kb,
    unsigned short* __restrict__ Vt) {
  __shared__ unsigned short vst[HH][72];   // V-tile transpose staging
  const int tid = threadIdx.x;
  const int lane = tid & 63;
  const int wid = tid >> 6;
  const int g = lane >> 4;
  const int m = lane & 15;
  const long r0 = (long)blockIdx.x * 64;
  const long rw = r0 + wid * 16;

  f32x4 acc[3][6];
#pragma unroll
  for (int w = 0; w < 3; ++w)
#pragma unroll
    for (int nf = 0; nf < 6; ++nf) { acc[w][nf][0] = 0.f; acc[w][nf][1] = 0.f; acc[w][nf][2] = 0.f; acc[w][nf][3] = 0.f; }

  const float* xrow = x + (rw + m) * DD;
  for (int ks = 0; ks < DD / 32; ++ks) {
    const int k0 = ks * 32 + g * 8;
    f32x4 a0 = *(const f32x4*)(xrow + k0);
    f32x4 a1 = *(const f32x4*)(xrow + k0 + 4);
    bf16x8 a;
#pragma unroll
    for (int j = 0; j < 4; ++j) { a[j] = (short)f2bf(a0[j]); a[4 + j] = (short)f2bf(a1[j]); }
#pragma unroll
    for (int w = 0; w < 3; ++w)
#pragma unroll
      for (int nf = 0; nf < 6; ++nf) {
        const bf16x8 wf = *(const bf16x8*)(Wt + (w * HH + nf * 16 + m) * DD + k0);
        acc[w][nf] = __builtin_amdgcn_mfma_f32_16x16x32_bf16(a, wf, acc[w][nf], 0, 0, 0);
      }
  }
  // Q,K row-major bf16 [B*T][96]; V -> LDS transpose
#pragma unroll
  for (int nf = 0; nf < 6; ++nf)
#pragma unroll
    for (int r = 0; r < 4; ++r) {
      long row = rw + 4 * g + r;
      Qb[row * HH + nf * 16 + m] = f2bf(acc[0][nf][r]);
      Kb[row * HH + nf * 16 + m] = f2bf(acc[1][nf][r]);
      vst[nf * 16 + m][wid * 16 + 4 * g + r] = f2bf(acc[2][nf][r]);
    }
  __syncthreads();
  // Vt[b][h][t] bf16, coalesced
  const int bidx = (int)(r0 >> 11);
  const int t0 = (int)(r0 & 2047);
#pragma unroll
  for (int j = 0; j < 3; ++j) {
    int flat = tid + j * 256;            // 96*64/8 = 768 chunks
    int h = flat >> 3;
    int t8 = (flat & 7) * 8;
    bf16x8 v = *(const bf16x8*)(&vst[h][t8]);
    *(bf16x8*)(Vt + ((long)(bidx * HH + h) * TT + t0 + t8)) = v;
  }
}

// ---------------- flash attention ----------------
// grid (32, 16) = (q-tile, batch); block 256 = 4 waves x 16 q-rows.
// Computes S^T = K*Q^T so softmax is column-wise (in-lane + shfl_xor 16/32),
// and P feeds PV directly from registers (slot-permutation of k is legal as
// long as A and B use the same (group,slot)->k map).
__global__ __launch_bounds__(256) void attn(
    const unsigned short* __restrict__ Qb, const unsigned short* __restrict__ Kb,
    const unsigned short* __restrict__ Vt, float* __restrict__ out) {
  __shared__ unsigned short vlds[HH][72];
  const int tid = threadIdx.x;
  const int lane = tid & 63;
  const int wid = tid >> 6;
  const int g = lane >> 4;
  const int c = lane & 15;
  const int qt = (int)gridDim.x - 1 - (int)blockIdx.x;   // heavy tiles first
  const int b = blockIdx.y;
  const int q0w = qt * 64 + wid * 16;

  bf16x8 qf[3];
  const unsigned short* qrow = Qb + (long)(b * TT + q0w + c) * HH;
#pragma unroll
  for (int ks = 0; ks < 3; ++ks) qf[ks] = *(const bf16x8*)(qrow + ks * 32 + g * 8);

  f32x4 o[6];
#pragma unroll
  for (int nf = 0; nf < 6; ++nf) { o[nf][0] = 0.f; o[nf][1] = 0.f; o[nf][2] = 0.f; o[nf][3] = 0.f; }
  float m_run = -1e30f, l_run = 0.f;
  const float SCL = 0.10206207261596577f * 1.44269504088896f;  // HS^-0.5 * log2(e)

  for (int kt = 0; kt <= qt; ++kt) {
    const int kv0 = kt * 64;
    __syncthreads();                       // protect vlds from previous iteration readers
#pragma unroll
    for (int j = 0; j < 3; ++j) {          // stage V tile: Vt rows -> vlds rows, no transpose
      int flat = tid + j * 256;
      int h = flat >> 3;
      int k8 = (flat & 7) * 8;
      bf16x8 v = *(const bf16x8*)(Vt + ((long)(b * HH + h) * TT + kv0 + k8));
      *(bf16x8*)(&vlds[h][k8]) = v;
    }
    __syncthreads();

    f32x4 s[4];
#pragma unroll
    for (int mf = 0; mf < 4; ++mf) { s[mf][0] = 0.f; s[mf][1] = 0.f; s[mf][2] = 0.f; s[mf][3] = 0.f; }
#pragma unroll
    for (int ks = 0; ks < 3; ++ks)
#pragma unroll
      for (int mf = 0; mf < 4; ++mf) {
        bf16x8 kfr = *(const bf16x8*)(Kb + (long)(b * TT + kv0 + mf * 16 + c) * HH + ks * 32 + g * 8);
        s[mf] = __builtin_amdgcn_mfma_f32_16x16x32_bf16(kfr, qf[ks], s[mf], 0, 0, 0);
      }

    // scale (log2-domain) + causal mask (only diagonal tile has any masked element)
    const int qcol = q0w + c;
    float smax = -1e30f;
#pragma unroll
    for (int mf = 0; mf < 4; ++mf)
#pragma unroll
      for (int r = 0; r < 4; ++r) {
        float v = s[mf][r] * SCL;
        if (kt == qt && (kv0 + mf * 16 + 4 * g + r) > qcol) v = -1e30f;
        s[mf][r] = v;
        smax = fmaxf(smax, v);
      }
    smax = fmaxf(smax, __shfl_xor(smax, 16));
    smax = fmaxf(smax, __shfl_xor(smax, 32));
    const float m_new = fmaxf(m_run, smax);
    const float corr = __builtin_amdgcn_exp2f(m_run - m_new);
    float rsum = 0.f;
    unsigned short pb[4][4];
#pragma unroll
    for (int mf = 0; mf < 4; ++mf)
#pragma unroll
      for (int r = 0; r < 4; ++r) {
        float p = __builtin_amdgcn_exp2f(s[mf][r] - m_new);
        rsum += p;
        pb[mf][r] = f2bf(p);
      }
    rsum += __shfl_xor(rsum, 16);
    rsum += __shfl_xor(rsum, 32);
    l_run = l_run * corr + rsum;
    m_run = m_new;
#pragma unroll
    for (int r = 0; r < 4; ++r) {          // rescale O rows (row q-index = 4g+r, stats live at lane c=4g+r)
      float cr = __shfl(corr, 4 * g + r);
#pragma unroll
      for (int nf = 0; nf < 6; ++nf) o[nf][r] *= cr;
    }
    // PV: A-slot (g,i) -> kv = 4g + (i&3) + 16*(2kf + (i>>2)); B loaded with same map
#pragma unroll
    for (int kf = 0; kf < 2; ++kf) {
      bf16x8 a;
#pragma unroll
      for (int i = 0; i < 8; ++i) a[i] = (short)pb[2 * kf + (i >> 2)][i & 3];
#pragma unroll
      for (int nf = 0; nf < 6; ++nf) {
        int hh = nf * 16 + c;
        bf16x4 lo = *(const bf16x4*)(&vlds[hh][kf * 32 + 4 * g]);
        bf16x4 hi = *(const bf16x4*)(&vlds[hh][kf * 32 + 4 * g + 16]);
        bf16x8 vf = __builtin_shufflevector(lo, hi, 0, 1, 2, 3, 4, 5, 6, 7);
        o[nf] = __builtin_amdgcn_mfma_f32_16x16x32_bf16(a, vf, o[nf], 0, 0, 0);
      }
    }
  }

  const float inv = 1.0f / l_run;
#pragma unroll
  for (int r = 0; r < 4; ++r) {
    float ivr = __shfl(inv, 4 * g + r);
    long orow = (long)(b * TT + q0w + 4 * g + r) * HH;
#pragma unroll
    for (int nf = 0; nf < 6; ++nf) out[orow + nf * 16 + c] = o[nf][r] * ivr;
  }
}

extern "C" void kernel_launch(void* const* d_in, const int* in_sizes, int n_in,
                              void* d_out, int out_size, void* d_ws, size_t ws_size,
                              hipStream_t stream) {
  const float* x  = (const float*)d_in[0];
  const float* Wk = (const float*)d_in[1];
  const float* Wq = (const float*)d_in[2];
  const float* Wv = (const float*)d_in[3];
  float* out = (float*)d_out;

  unsigned short* Wt = (unsigned short*)d_ws;        // 3*96*768 bf16 = 442 KB
  unsigned short* Qb = Wt + 3 * HH * DD;             // [B*T][96] bf16
  unsigned short* Kb = Qb + (long)BB * TT * HH;      // [B*T][96] bf16
  unsigned short* Vt = Kb + (long)BB * TT * HH;      // [B][96][T] bf16 (transposed)

  wconv<<<dim3((3 * HH * DD + 255) / 256), dim3(256), 0, stream>>>(Wk, Wq, Wv, Wt);
  qkv_proj<<<dim3(BB * TT / 64), dim3(256), 0, stream>>>(x, Wt, Qb, Kb, Vt);
  attn<<<dim3(TT / 64, BB), dim3(256), 0, stream>>>(Qb, Kb, Vt, out);
}